// Round 16
// baseline (3266.571 us; speedup 1.0000x reference)
//
#include <hip/hip_runtime.h>
#include <math.h>

// Problem constants
#define B_ROWS 8192
#define S_LEN  512
#define H_DIM  256
#define G3     768          // 3*H
#define P_DIM  96
#define TB     32           // batch rows per block

typedef __attribute__((ext_vector_type(8))) _Float16 half8;  // 8 f16 (4 VGPRs)
typedef __attribute__((ext_vector_type(4))) float floatx4;   // MFMA C/D frag

__device__ __forceinline__ float sigmoid_fast(float v) {
    return 1.0f / (1.0f + __expf(-v));
}
__device__ __forceinline__ float tanh_fast(float v) {
    return 1.0f - 2.0f / (__expf(2.0f * v) + 1.0f);
}
__device__ __forceinline__ unsigned short f32_f16(float f) {
    _Float16 h = (_Float16)f;                 // RTN
    return __builtin_bit_cast(unsigned short, h);
}
// A-frag slot swizzle: bit permutation (b5,b4,b3,b2,b1,b0)->(b5,b1,b0,b4,b3,b2).
// Chosen so fsw(d)%8 = (b4,b3,b2) — exactly the bits that VARY across a
// wave's h-scatter at fixed r (q's two bits + cg0) -> the 8 written slots
// hit 8 DISTINCT bank groups (old rot3 hit only 4 -> structural 4-way
// conflict on every ds_write_b16; 2.0e8 conflict cycles/dispatch).
// Reads are swizzle-insensitive (any bijection spreads 64x16B evenly).
__device__ __forceinline__ int fsw(int d) {
    return ((d >> 2) & 7) | ((d & 3) << 3) | (d & 32);
}

// -------- One-time weight pack: W_hh -> per-lane MFMA B-fragments (hi/lo fp16).
// h in (-1,1) is sent as SINGLE fp16.  W precision policy (round-11-proven):
//   k=0..223 (kc=0..6): SINGLE fp16 hi only (kc0-5 streamed, kc6 from LDS)
//   k=224..255 (kc=7, registers): split hi+lo (~2^-22 capture)
// B[k][n] = W_hh[n][k].  16x16x32 B-frag: lane holds B[n=lane&15][k=quad*8+j].
// Tile index = (k>>5)*48 + (j>>4); lane = (j&15) | (((k>>3)&3)<<4); short = k&7.
// Also WoT[k][p] = W_out[p][k]; also zeroes the (now unused) sync counter.
__global__ void pack_weights(const float* __restrict__ W_hh,
                             const float* __restrict__ W_out,
                             unsigned short* __restrict__ Bh,
                             unsigned short* __restrict__ Bl,
                             float* __restrict__ WoT,
                             unsigned int* __restrict__ ctr) {
    const int j = blockIdx.x;    // gate col 0..767
    const int k = threadIdx.x;   // h idx   0..255
    const float wv = W_hh[j * H_DIM + k];
    const unsigned short hi = f32_f16(wv);
    const float hf = (float)__builtin_bit_cast(_Float16, hi);
    const unsigned short lo = f32_f16(wv - hf);
    const int idx = (((k >> 5) * 48 + (j >> 4)) * 64 +
                     ((j & 15) | (((k >> 3) & 3) << 4))) * 8 + (k & 7);
    Bh[idx] = hi;
    Bl[idx] = lo;
    if (j < P_DIM) WoT[k * P_DIM + j] = W_out[j * H_DIM + k];
    if (j == 0 && k == 0) *ctr = 0u;   // d_ws is re-poisoned every launch
}

// LDS layout (84 KiB total; 1 block/CU):
//   [0,       32768)  A-fragments (fp16), double-buffered:
//                     buf*16384 + chunk(kc*2+mt)*1024 + slot*16 + short*2
//                     (slot = fsw'd fragment-lane index)
//   [32768,   36864)  xtile[2][32][16] fp32
//   [36864,   86016)  W cache: 48 tiles x 1 KiB = kc=6 hi (index T=g*16+wv)
#define A_OFF   0
#define X_OFF   32768
#define W_OFF   36864
#define LDS_SZ  86016

// Issue 3 streamed hi-tile loads for one kc (stay in flight until MFMA use).
__device__ __forceinline__ void gissue1(half8 (&BH)[3],
                                        const unsigned short* (&pbh)[3],
                                        int kc) {
#pragma unroll
    for (int g = 0; g < 3; ++g)
        BH[g] = *(const half8*)(pbh[g] + (size_t)kc * 24576);
}

__device__ __forceinline__ void ahread(half8 (&AH)[2], const char* Ac,
                                       int kc, int rl) {
#pragma unroll
    for (int mt = 0; mt < 2; ++mt)
        AH[mt] = *(const half8*)(Ac + (kc * 2 + mt) * 1024 + rl * 16);
}

// Single-precision kc block: 6 MFMAs (hi product only).
__device__ __forceinline__ void kcmfma1(floatx4 (&acc)[3][2],
                                        const half8 (&AH)[2],
                                        const half8 (&BH)[3]) {
#pragma unroll
    for (int g = 0; g < 3; ++g) {
        acc[g][0] = __builtin_amdgcn_mfma_f32_16x16x32_f16(AH[0], BH[g], acc[g][0], 0, 0, 0);
        acc[g][1] = __builtin_amdgcn_mfma_f32_16x16x32_f16(AH[1], BH[g], acc[g][1], 0, 0, 0);
    }
}

// Split-precision kc block: 12 MFMAs (hi+lo) — used for kc7 (registers).
__device__ __forceinline__ void kcmfma2(floatx4 (&acc)[3][2],
                                        const half8 (&AH)[2],
                                        const half8 (&BH)[3],
                                        const half8 (&BL)[3]) {
#pragma unroll
    for (int g = 0; g < 3; ++g) {
        acc[g][0] = __builtin_amdgcn_mfma_f32_16x16x32_f16(AH[0], BH[g], acc[g][0], 0, 0, 0);
        acc[g][1] = __builtin_amdgcn_mfma_f32_16x16x32_f16(AH[1], BH[g], acc[g][1], 0, 0, 0);
        acc[g][0] = __builtin_amdgcn_mfma_f32_16x16x32_f16(AH[0], BL[g], acc[g][0], 0, 0, 0);
        acc[g][1] = __builtin_amdgcn_mfma_f32_16x16x32_f16(AH[1], BL[g], acc[g][1], 0, 0, 0);
    }
}

// Main persistent GRU kernel (round 16 = round 15 + fsw scatter swizzle).
// r15 counters: SQ_LDS_BANK_CONFLICT 2.0e8 ~= 1540 cyc/CU/step ~= 10% of
// wall.  Analytic source: rot3 mapped the 8 scatter slots onto only 4 LDS
// bank groups (cg1 = wave parity is constant per wave).  fsw puts the three
// per-wave-varying bits of d into the bank-group bits -> conflict-free
// writes.  Reader and writer both use fsw; numerics unchanged.
// grid = 256 (1 block/CU), block = 1024 (16 waves, 4 waves/SIMD).
__global__ __launch_bounds__(1024)
__attribute__((amdgpu_waves_per_eu(4, 4)))
void gru_mfma(const float* __restrict__ x,
              const float* __restrict__ W_ih,
              const float* __restrict__ b_ih,
              const float* __restrict__ b_hh,
              const unsigned short* __restrict__ Bh,
              const unsigned short* __restrict__ Bl,
              const float* __restrict__ WoT,   // [256][96]
              const float* __restrict__ b_out,
              float* __restrict__ out,
              unsigned int* __restrict__ ctr) {
    (void)ctr;   // heartbeat removed; counter unused
    __shared__ __align__(16) char smem[LDS_SZ];

    const int tid  = threadIdx.x;
    const int wv   = tid >> 6;     // wave 0..15; owns gate-cols g*256 + wv*16 + c
    const int lane = tid & 63;
    const int q    = lane >> 4;    // quad
    const int c    = lane & 15;
    const int row0 = blockIdx.x * TB;

    // Per-thread gate params; col = 256*g + 16*wv + c
    float wih[3], bcc[2], bihn, bhhn;
#pragma unroll
    for (int g = 0; g < 3; ++g) {
        const int col = g * H_DIM + wv * 16 + c;
        wih[g] = W_ih[col];
        if (g < 2) {
            bcc[g] = b_ih[col] + b_hh[col];
        } else {
            bihn = b_ih[col];
            bhhn = b_hh[col];
        }
    }

    // Streamed-tile base pointers (per wave/lane); tile index T = g*16 + wv.
    const unsigned short* pbh[3];
#pragma unroll
    for (int g = 0; g < 3; ++g)
        pbh[g] = Bh + (size_t)(g * 16 + wv) * 512 + lane * 8;

    // Register-resident weight tiles: kc=7 hi+lo.  (24 VGPRs)
    half8 r7h[3], r7l[3];
#pragma unroll
    for (int g = 0; g < 3; ++g) {
        const size_t toff = (size_t)(g * 16 + wv) * 512 + lane * 8;
        r7h[g] = *(const half8*)(Bh + toff + 7 * 24576);
        r7l[g] = *(const half8*)(Bl + toff + 7 * 24576);
    }

    // LDS weight cache staging: 48 tiles = kc=6 hi only.
    for (int i = tid; i < 48 * 64; i += 1024) {
        const int slot = i >> 6, l16 = i & 63;
        const unsigned short* src = Bh + (size_t)(288 + slot) * 512 + l16 * 8;
        *(uint4*)(smem + W_OFF + slot * 1024 + l16 * 16) = *(const uint4*)src;
    }

    // Zero both A-frag buffers (h0 = 0) and stage x for t=0..15.
    for (int i = tid; i < 8192; i += 1024) ((int*)(smem + A_OFF))[i] = 0;
    float* xt = (float*)(smem + X_OFF);
    if (tid < 512) {
        const int r = tid >> 4, t2 = tid & 15;
        xt[r * 16 + t2] = x[(size_t)(row0 + r) * S_LEN + t2];
    }
    __syncthreads();

    // h_old in C-frag layout: element (mt,reg) = h[4q+reg+16mt][16wv+c]
    float h_own[2][4];
#pragma unroll
    for (int mt = 0; mt < 2; ++mt)
#pragma unroll
        for (int r = 0; r < 4; ++r) h_own[mt][r] = 0.0f;

    const int rl = fsw(lane);

    // Loop-invariant precompute.
    const int hchunk = (wv >> 1) * 2;           // A-chunk pair this wave scatters
    const int cg     = 2 * (wv & 1) + (c >> 3); // col-group within chunk
    int soff[4];                                // [r] -> fsw(d)*16 + (c&7)*2
#pragma unroll
    for (int r = 0; r < 4; ++r) {
        const int d = (q * 4 + r) | (cg << 4);
        soff[r] = fsw(d) * 16 + (c & 7) * 2;
    }
    int xbase[2][4];                            // [mt][r] -> (q*4+r+16mt)*16
#pragma unroll
    for (int mt = 0; mt < 2; ++mt)
#pragma unroll
        for (int r = 0; r < 4; ++r)
            xbase[mt][r] = (q * 4 + r + 16 * mt) * 16;
    const char* w6base[3];                      // kc6 hi tile, T = g*16+wv
#pragma unroll
    for (int g = 0; g < 3; ++g)
        w6base[g] = smem + W_OFF + (g * 16 + wv) * 1024 + lane * 16;

    // Pipeline buffers (static names only — rule: no runtime indexing).
    half8 b0h[3], b1h[3];
    half8 ahA[2], ahB[2];

    // Prologue: kc=0 of step 0 in flight before the loop.
    gissue1(b0h, pbh, 0);

#pragma unroll 1
    for (int t = 0; t < S_LEN; ++t) {
        // Defeat LICM of the (t-invariant) streamed loads.
#pragma unroll
        for (int g = 0; g < 3; ++g)
            asm volatile("" : "+v"(pbh[g]));

        const int cur = t & 1, nxt = cur ^ 1;
        const char* Ac = smem + A_OFF + cur * 16384;

        ahread(ahA, Ac, 0, rl);            // A-frags for kc=0
        gissue1(b1h, pbh, 1);              // kc=1 stream in flight

        // x for my 8 rows (LDS broadcast); xidx is wave-uniform per step.
        const int xidx = ((t >> 4) & 1) * 512 + (t & 15);
        float xr[2][4];
#pragma unroll
        for (int mt = 0; mt < 2; ++mt)
#pragma unroll
            for (int r = 0; r < 4; ++r)
                xr[mt][r] = xt[xbase[mt][r] + xidx];

        // C frags [gate][mt]; fold x-side pre-activation + bias into init.
        floatx4 acc[3][2];
#pragma unroll
        for (int mt = 0; mt < 2; ++mt)
#pragma unroll
            for (int r = 0; r < 4; ++r) {
                acc[0][mt][r] = fmaf(xr[mt][r], wih[0], bcc[0]);
                acc[1][mt][r] = fmaf(xr[mt][r], wih[1], bcc[1]);
                acc[2][mt][r] = bhhn;
            }

        // ---- Pipelined kc ladder (single-fp16 stream): consume kc,
        //      stream kc+1, read A(kc+1) ----
        ahread(ahB, Ac, 1, rl);
        kcmfma1(acc, ahA, b0h);                           // kc0
        gissue1(b0h, pbh, 2);
        ahread(ahA, Ac, 2, rl);
        kcmfma1(acc, ahB, b1h);                           // kc1
        gissue1(b1h, pbh, 3);
        ahread(ahB, Ac, 3, rl);
        kcmfma1(acc, ahA, b0h);                           // kc2
        gissue1(b0h, pbh, 4);
        ahread(ahA, Ac, 4, rl);
        kcmfma1(acc, ahB, b1h);                           // kc3
        gissue1(b1h, pbh, 5);
        ahread(ahB, Ac, 5, rl);
        kcmfma1(acc, ahA, b0h);                           // kc4
        ahread(ahA, Ac, 6, rl);
        kcmfma1(acc, ahB, b1h);                           // kc5

        // ---- kc6: hi from the LDS cache (single precision) ----
        {
            half8 w6h[3];
#pragma unroll
            for (int g = 0; g < 3; ++g)
                w6h[g] = *(const half8*)(w6base[g]);
            ahread(ahB, Ac, 7, rl);
            kcmfma1(acc, ahA, w6h);                       // kc6
        }

        // Prefetch next step's kc0 while kc7 + gates + barrier run.
        gissue1(b0h, pbh, 0);
        kcmfma2(acc, ahB, r7h, r7l);                      // kc7 (split)

        // Gates + h update (in-register); scatter next A-frags (fsw-swizzled).
        char* Anx = smem + A_OFF + nxt * 16384;
#pragma unroll
        for (int mt = 0; mt < 2; ++mt) {
            char* ch = Anx + (hchunk + mt) * 1024;        // chunk kc = wv>>1
#pragma unroll
            for (int r = 0; r < 4; ++r) {
                const float rr  = sigmoid_fast(acc[0][mt][r]);
                const float zz  = sigmoid_fast(acc[1][mt][r]);
                const float inn = fmaf(xr[mt][r], wih[2], bihn);
                const float nn  = tanh_fast(fmaf(rr, acc[2][mt][r], inn));
                const float hv  = (1.0f - zz) * nn + zz * h_own[mt][r];
                h_own[mt][r] = hv;
                *(unsigned short*)(ch + soff[r]) = f32_f16(hv);
            }
        }

        // Re-stage x for the next 16 steps (into the idle x buffer).
        const bool tick = ((t & 15) == 15) && (t != S_LEN - 1);
        if (tick && tid < 512) {
            const int r = tid >> 4, t2 = tid & 15;
            xt[((((t + 1) >> 4) & 1) * 32 + r) * 16 + t2] =
                x[(size_t)(row0 + r) * S_LEN + (t + 1) + t2];
        }
        __syncthreads();   // single barrier: next A-frags + x tile visible
    }

    // -------- Epilogue: dump final h (fp32, from registers) and project.
    float* hfin = (float*)(smem);   // reuse A region: [32][256] = 32 KiB
#pragma unroll
    for (int mt = 0; mt < 2; ++mt)
#pragma unroll
        for (int r = 0; r < 4; ++r) {
            const int m = q * 4 + r + 16 * mt;
            const int k = wv * 16 + c;
            hfin[m * H_DIM + k] = h_own[mt][r];
        }
    __syncthreads();

    if (tid < 256) {
        const int cid   = tid & 63;
        const int rid   = tid >> 6;
        const int myrow = rid * 8;
        const int pA    = cid;
        const int pB    = 64 + cid;
        const bool hasB = (cid < 32);
        float accA[8], accB[8];
#pragma unroll
        for (int rr = 0; rr < 8; ++rr) { accA[rr] = 0.0f; accB[rr] = 0.0f; }

        for (int k = 0; k < H_DIM; k += 4) {
            float4 hv[8];
#pragma unroll
            for (int rr = 0; rr < 8; ++rr)
                hv[rr] = *(const float4*)&hfin[(myrow + rr) * H_DIM + k];
            float wA[4], wB[4];
#pragma unroll
            for (int kk = 0; kk < 4; ++kk) {
                wA[kk] = WoT[(size_t)(k + kk) * P_DIM + pA];
                wB[kk] = hasB ? WoT[(size_t)(k + kk) * P_DIM + pB] : 0.0f;
            }
#pragma unroll
            for (int kk = 0; kk < 4; ++kk)
#pragma unroll
                for (int rr = 0; rr < 8; ++rr) {
                    const float hvv = (&hv[rr].x)[kk];
                    accA[rr] = fmaf(hvv, wA[kk], accA[rr]);
                    accB[rr] = fmaf(hvv, wB[kk], accB[rr]);
                }
        }
        const float boA = b_out[pA];
        const float boB = hasB ? b_out[pB] : 0.0f;
#pragma unroll
        for (int rr = 0; rr < 8; ++rr) {
            const size_t orow = (size_t)(row0 + myrow + rr) * P_DIM;
            out[orow + pA] = accA[rr] + boA;
            if (hasB) out[orow + pB] = accB[rr] + boB;
        }
    }
}

// -------- fp32 fallback — used only if ws_size is too small.
__global__ __launch_bounds__(256, 1)
void gru_fallback(const float* __restrict__ x,
                  const float* __restrict__ W_ih,
                  const float* __restrict__ Whh,
                  const float* __restrict__ b_ih,
                  const float* __restrict__ b_hh,
                  const float* __restrict__ Wout,
                  const float* __restrict__ b_out,
                  float* __restrict__ out) {
    __shared__ float hbuf[2][TB][H_DIM];

    const int tid   = threadIdx.x;
    const int cid   = tid & 63;
    const int rid   = tid >> 6;
    const int row0  = blockIdx.x * TB;
    const int myrow = rid * 8;
    const int c0    = cid * 4;

    float wih[3][4], bc[2][4], bihn[4], bhhn[4];
#pragma unroll
    for (int cc = 0; cc < 4; ++cc) {
        const int j = c0 + cc;
        wih[0][cc] = W_ih[j];
        wih[1][cc] = W_ih[H_DIM + j];
        wih[2][cc] = W_ih[2 * H_DIM + j];
        bc[0][cc]  = b_ih[j] + b_hh[j];
        bc[1][cc]  = b_ih[H_DIM + j] + b_hh[H_DIM + j];
        bihn[cc]   = b_ih[2 * H_DIM + j];
        bhhn[cc]   = b_hh[2 * H_DIM + j];
    }
    for (int i = tid; i < TB * H_DIM; i += 256) (&hbuf[0][0][0])[i] = 0.0f;
    float h_own[8][4];
#pragma unroll
    for (int rr = 0; rr < 8; ++rr)
#pragma unroll
        for (int cc = 0; cc < 4; ++cc) h_own[rr][cc] = 0.0f;
    __syncthreads();

    int p = 0;
    for (int t = 0; t < S_LEN; ++t) {
        float xv[8];
#pragma unroll
        for (int rr = 0; rr < 8; ++rr)
            xv[rr] = x[(size_t)(row0 + myrow + rr) * S_LEN + t];

        float acc[3][8][4];
#pragma unroll
        for (int rr = 0; rr < 8; ++rr)
#pragma unroll
            for (int cc = 0; cc < 4; ++cc) {
                acc[0][rr][cc] = fmaf(xv[rr], wih[0][cc], bc[0][cc]);
                acc[1][rr][cc] = fmaf(xv[rr], wih[1][cc], bc[1][cc]);
                acc[2][rr][cc] = bhhn[cc];
            }
        const float* hb = &hbuf[p][0][0];
        for (int k = 0; k < H_DIM; k += 4) {
            float4 hv[8];
#pragma unroll
            for (int rr = 0; rr < 8; ++rr)
                hv[rr] = *(const float4*)(hb + (myrow + rr) * H_DIM + k);
#pragma unroll
            for (int g = 0; g < 3; ++g)
#pragma unroll
                for (int kk = 0; kk < 4; ++kk) {
                    float wrow[4];
#pragma unroll
                    for (int cc = 0; cc < 4; ++cc)
                        wrow[cc] = Whh[(size_t)(g * H_DIM + c0 + cc) * H_DIM + k + kk];
#pragma unroll
                    for (int rr = 0; rr < 8; ++rr) {
                        const float hvv = (&hv[rr].x)[kk];
#pragma unroll
                        for (int cc = 0; cc < 4; ++cc)
                            acc[g][rr][cc] = fmaf(hvv, wrow[cc], acc[g][rr][cc]);
                    }
                }
        }
#pragma unroll
        for (int rr = 0; rr < 8; ++rr) {
            float4 hnew;
#pragma unroll
            for (int cc = 0; cc < 4; ++cc) {
                const float r_  = sigmoid_fast(acc[0][rr][cc]);
                const float z_  = sigmoid_fast(acc[1][rr][cc]);
                const float i_n = fmaf(xv[rr], wih[2][cc], bihn[cc]);
                const float n_  = tanh_fast(fmaf(r_, acc[2][rr][cc], i_n));
                const float hv2 = (1.0f - z_) * n_ + z_ * h_own[rr][cc];
                h_own[rr][cc] = hv2;
                (&hnew.x)[cc] = hv2;
            }
            *(float4*)&hbuf[1 - p][myrow + rr][c0] = hnew;
        }
        __syncthreads();
        p ^= 1;
    }

    const int  pA   = cid;
    const int  pB   = 64 + cid;
    const bool hasB = (cid < 32);
    float accA[8], accB[8];
#pragma unroll
    for (int rr = 0; rr < 8; ++rr) { accA[rr] = 0.0f; accB[rr] = 0.0f; }
    for (int k = 0; k < H_DIM; k += 4) {
        float4 hv[8];
#pragma unroll
        for (int rr = 0; rr < 8; ++rr)
            hv[rr] = *(const float4*)&hbuf[p][myrow + rr][k];
        float wA[4], wB[4];
#pragma unroll
        for (int kk = 0; kk < 4; ++kk) {
            wA[kk] = Wout[(size_t)pA * H_DIM + k + kk];
            wB[kk] = hasB ? Wout[(size_t)pB * H_DIM + k + kk] : 0.0f;
        }
#pragma unroll
        for (int kk = 0; kk < 4; ++kk)
#pragma unroll
            for (int rr = 0; rr < 8; ++rr) {
                const float hvv = (&hv[rr].x)[kk];
                accA[rr] = fmaf(hvv, wA[kk], accA[rr]);
                accB[rr] = fmaf(hvv, wB[kk], accB[rr]);
            }
    }
    const float boA = b_out[pA];
    const float boB = hasB ? b_out[pB] : 0.0f;
#pragma unroll
    for (int rr = 0; rr < 8; ++rr) {
        const size_t orow = (size_t)(row0 + myrow + rr) * P_DIM;
        out[orow + pA] = accA[rr] + boA;
        if (hasB) out[orow + pB] = accB[rr] + boB;
    }
}

extern "C" void kernel_launch(void* const* d_in, const int* in_sizes, int n_in,
                              void* d_out, int out_size, void* d_ws, size_t ws_size,
                              hipStream_t stream) {
    const float* x     = (const float*)d_in[0];
    const float* W_ih  = (const float*)d_in[1];
    const float* W_hh  = (const float*)d_in[2];
    const float* b_ih  = (const float*)d_in[3];
    const float* b_hh  = (const float*)d_in[4];
    const float* W_out = (const float*)d_in[5];
    const float* b_out = (const float*)d_in[6];
    float* out = (float*)d_out;

    const size_t bpack_elems = 8 * 48 * 64 * 8;          // 196608 f16 per matrix
    const size_t wot_elems   = (size_t)H_DIM * P_DIM;    // 24576 fp32
    const size_t ctr_off = bpack_elems * 2 * sizeof(unsigned short) * 2 +
                           wot_elems * sizeof(float);    // 1671168 B (16-aligned)
    const size_t need = ctr_off + sizeof(unsigned int);

    if (ws_size >= need) {
        unsigned short* Bh = (unsigned short*)d_ws;
        unsigned short* Bl = Bh + bpack_elems * 2;
        float* WoT = (float*)(Bl + bpack_elems * 2);
        unsigned int* ctr = (unsigned int*)((char*)d_ws + ctr_off);
        pack_weights<<<G3, H_DIM, 0, stream>>>(W_hh, W_out, Bh, Bl, WoT, ctr);
        gru_mfma<<<B_ROWS / TB, 1024, 0, stream>>>(x, W_ih, b_ih, b_hh,
                                                   Bh, Bl, WoT, b_out, out, ctr);
    } else {
        gru_fallback<<<B_ROWS / TB, 256, 0, stream>>>(x, W_ih, W_hh, b_ih, b_hh,
                                                      W_out, b_out, out);
    }
}

// Round 17
// 3107.551 us; speedup vs baseline: 1.0512x; 1.0512x over previous
//
#include <hip/hip_runtime.h>
#include <math.h>

// Problem constants
#define B_ROWS 8192
#define S_LEN  512
#define H_DIM  256
#define G3     768          // 3*H
#define P_DIM  96
#define TB     32           // batch rows per block

typedef __attribute__((ext_vector_type(8))) _Float16 half8;  // 8 f16 (4 VGPRs)
typedef __attribute__((ext_vector_type(4))) float floatx4;   // MFMA C/D frag

__device__ __forceinline__ float sigmoid_fast(float v) {
    return 1.0f / (1.0f + __expf(-v));
}
__device__ __forceinline__ float tanh_fast(float v) {
    return 1.0f - 2.0f / (__expf(2.0f * v) + 1.0f);
}
__device__ __forceinline__ unsigned short f32_f16(float f) {
    _Float16 h = (_Float16)f;                 // RTN
    return __builtin_bit_cast(unsigned short, h);
}
// Involutive 6-bit lane rotation: spreads scatter dest-lanes across bank groups.
// NOTE (r16 lesson): with the [slot*16] A-frag layout the ds_read_b128 bank
// group is slot%8; ANY bijection places 8 lanes per group per read, so the
// read-conflict floor is layout-inherent.  fsw (write-optimal) regressed
// overall (3117->3267, conflicts only -17%): read phasing dominates.  rot3
// is the measured optimum of the tested swizzles.
__device__ __forceinline__ int rot3(int l) { return ((l << 3) | (l >> 3)) & 63; }

// -------- One-time weight pack: W_hh -> per-lane MFMA B-fragments (hi/lo fp16).
// h in (-1,1) is sent as SINGLE fp16.  W precision policy (round-11-proven):
//   k=0..223 (kc=0..6): SINGLE fp16 hi only (kc0-5 streamed, kc6 from LDS)
//   k=224..255 (kc=7, registers): split hi+lo (~2^-22 capture)
// B[k][n] = W_hh[n][k].  16x16x32 B-frag: lane holds B[n=lane&15][k=quad*8+j].
// Tile index = (k>>5)*48 + (j>>4); lane = (j&15) | (((k>>3)&3)<<4); short = k&7.
// Also WoT[k][p] = W_out[p][k]; also zeroes the (now unused) sync counter.
__global__ void pack_weights(const float* __restrict__ W_hh,
                             const float* __restrict__ W_out,
                             unsigned short* __restrict__ Bh,
                             unsigned short* __restrict__ Bl,
                             float* __restrict__ WoT,
                             unsigned int* __restrict__ ctr) {
    const int j = blockIdx.x;    // gate col 0..767
    const int k = threadIdx.x;   // h idx   0..255
    const float wv = W_hh[j * H_DIM + k];
    const unsigned short hi = f32_f16(wv);
    const float hf = (float)__builtin_bit_cast(_Float16, hi);
    const unsigned short lo = f32_f16(wv - hf);
    const int idx = (((k >> 5) * 48 + (j >> 4)) * 64 +
                     ((j & 15) | (((k >> 3) & 3) << 4))) * 8 + (k & 7);
    Bh[idx] = hi;
    Bl[idx] = lo;
    if (j < P_DIM) WoT[k * P_DIM + j] = W_out[j * H_DIM + k];
    if (j == 0 && k == 0) *ctr = 0u;   // d_ws is re-poisoned every launch
}

// LDS layout (84 KiB total; 1 block/CU):
//   [0,       32768)  A-fragments (fp16), double-buffered:
//                     buf*16384 + chunk(kc*2+mt)*1024 + slot*16 + short*2
//                     (slot = rot3'd fragment-lane index)
//   [32768,   36864)  xtile[2][32][16] fp32
//   [36864,   86016)  W cache: 48 tiles x 1 KiB = kc=6 hi (index T=g*16+wv)
#define A_OFF   0
#define X_OFF   32768
#define W_OFF   36864
#define LDS_SZ  86016

// Issue 3 streamed hi-tile loads for one kc (stay in flight until MFMA use).
__device__ __forceinline__ void gissue1(half8 (&BH)[3],
                                        const unsigned short* (&pbh)[3],
                                        int kc) {
#pragma unroll
    for (int g = 0; g < 3; ++g)
        BH[g] = *(const half8*)(pbh[g] + (size_t)kc * 24576);
}

__device__ __forceinline__ void ahread(half8 (&AH)[2], const char* Ac,
                                       int kc, int rl) {
#pragma unroll
    for (int mt = 0; mt < 2; ++mt)
        AH[mt] = *(const half8*)(Ac + (kc * 2 + mt) * 1024 + rl * 16);
}

// Single-precision kc block: 6 MFMAs (hi product only).
__device__ __forceinline__ void kcmfma1(floatx4 (&acc)[3][2],
                                        const half8 (&AH)[2],
                                        const half8 (&BH)[3]) {
#pragma unroll
    for (int g = 0; g < 3; ++g) {
        acc[g][0] = __builtin_amdgcn_mfma_f32_16x16x32_f16(AH[0], BH[g], acc[g][0], 0, 0, 0);
        acc[g][1] = __builtin_amdgcn_mfma_f32_16x16x32_f16(AH[1], BH[g], acc[g][1], 0, 0, 0);
    }
}

// Split-precision kc block: 12 MFMAs (hi+lo) — used for kc7 (registers).
__device__ __forceinline__ void kcmfma2(floatx4 (&acc)[3][2],
                                        const half8 (&AH)[2],
                                        const half8 (&BH)[3],
                                        const half8 (&BL)[3]) {
#pragma unroll
    for (int g = 0; g < 3; ++g) {
        acc[g][0] = __builtin_amdgcn_mfma_f32_16x16x32_f16(AH[0], BH[g], acc[g][0], 0, 0, 0);
        acc[g][1] = __builtin_amdgcn_mfma_f32_16x16x32_f16(AH[1], BH[g], acc[g][1], 0, 0, 0);
        acc[g][0] = __builtin_amdgcn_mfma_f32_16x16x32_f16(AH[0], BL[g], acc[g][0], 0, 0, 0);
        acc[g][1] = __builtin_amdgcn_mfma_f32_16x16x32_f16(AH[1], BL[g], acc[g][1], 0, 0, 0);
    }
}

// Main persistent GRU kernel (round 17 = round 15 exactly — the measured
// session optimum, 3117 us).  r16's fsw swizzle is reverted (read phasing
// regression).  Structural accounting at this state: MFMA issue 23.5% +
// VALU 61% + LDS-conflict serialization ~10% ~= 95% of wall; both issue
// pipes near-saturated at the allocator-pinned 64-VGPR budget.
// grid = 256 (1 block/CU), block = 1024 (16 waves, 4 waves/SIMD).
__global__ __launch_bounds__(1024)
__attribute__((amdgpu_waves_per_eu(4, 4)))
void gru_mfma(const float* __restrict__ x,
              const float* __restrict__ W_ih,
              const float* __restrict__ b_ih,
              const float* __restrict__ b_hh,
              const unsigned short* __restrict__ Bh,
              const unsigned short* __restrict__ Bl,
              const float* __restrict__ WoT,   // [256][96]
              const float* __restrict__ b_out,
              float* __restrict__ out,
              unsigned int* __restrict__ ctr) {
    (void)ctr;   // heartbeat removed; counter unused
    __shared__ __align__(16) char smem[LDS_SZ];

    const int tid  = threadIdx.x;
    const int wv   = tid >> 6;     // wave 0..15; owns gate-cols g*256 + wv*16 + c
    const int lane = tid & 63;
    const int q    = lane >> 4;    // quad
    const int c    = lane & 15;
    const int row0 = blockIdx.x * TB;

    // Per-thread gate params; col = 256*g + 16*wv + c
    float wih[3], bcc[2], bihn, bhhn;
#pragma unroll
    for (int g = 0; g < 3; ++g) {
        const int col = g * H_DIM + wv * 16 + c;
        wih[g] = W_ih[col];
        if (g < 2) {
            bcc[g] = b_ih[col] + b_hh[col];
        } else {
            bihn = b_ih[col];
            bhhn = b_hh[col];
        }
    }

    // Streamed-tile base pointers (per wave/lane); tile index T = g*16 + wv.
    const unsigned short* pbh[3];
#pragma unroll
    for (int g = 0; g < 3; ++g)
        pbh[g] = Bh + (size_t)(g * 16 + wv) * 512 + lane * 8;

    // Register-resident weight tiles: kc=7 hi+lo.  (24 VGPRs)
    half8 r7h[3], r7l[3];
#pragma unroll
    for (int g = 0; g < 3; ++g) {
        const size_t toff = (size_t)(g * 16 + wv) * 512 + lane * 8;
        r7h[g] = *(const half8*)(Bh + toff + 7 * 24576);
        r7l[g] = *(const half8*)(Bl + toff + 7 * 24576);
    }

    // LDS weight cache staging: 48 tiles = kc=6 hi only.
    for (int i = tid; i < 48 * 64; i += 1024) {
        const int slot = i >> 6, l16 = i & 63;
        const unsigned short* src = Bh + (size_t)(288 + slot) * 512 + l16 * 8;
        *(uint4*)(smem + W_OFF + slot * 1024 + l16 * 16) = *(const uint4*)src;
    }

    // Zero both A-frag buffers (h0 = 0) and stage x for t=0..15.
    for (int i = tid; i < 8192; i += 1024) ((int*)(smem + A_OFF))[i] = 0;
    float* xt = (float*)(smem + X_OFF);
    if (tid < 512) {
        const int r = tid >> 4, t2 = tid & 15;
        xt[r * 16 + t2] = x[(size_t)(row0 + r) * S_LEN + t2];
    }
    __syncthreads();

    // h_old in C-frag layout: element (mt,reg) = h[4q+reg+16mt][16wv+c]
    float h_own[2][4];
#pragma unroll
    for (int mt = 0; mt < 2; ++mt)
#pragma unroll
        for (int r = 0; r < 4; ++r) h_own[mt][r] = 0.0f;

    const int rl = rot3(lane);

    // Loop-invariant precompute.
    const int hchunk = (wv >> 1) * 2;           // A-chunk pair this wave scatters
    const int cg     = 2 * (wv & 1) + (c >> 3); // col-group within chunk
    int soff[4];                                // [r] -> rot3(d)*16 + (c&7)*2
#pragma unroll
    for (int r = 0; r < 4; ++r) {
        const int d = (q * 4 + r) | (cg << 4);
        soff[r] = rot3(d) * 16 + (c & 7) * 2;
    }
    int xbase[2][4];                            // [mt][r] -> (q*4+r+16mt)*16
#pragma unroll
    for (int mt = 0; mt < 2; ++mt)
#pragma unroll
        for (int r = 0; r < 4; ++r)
            xbase[mt][r] = (q * 4 + r + 16 * mt) * 16;
    const char* w6base[3];                      // kc6 hi tile, T = g*16+wv
#pragma unroll
    for (int g = 0; g < 3; ++g)
        w6base[g] = smem + W_OFF + (g * 16 + wv) * 1024 + lane * 16;

    // Pipeline buffers (static names only — rule: no runtime indexing).
    half8 b0h[3], b1h[3];
    half8 ahA[2], ahB[2];

    // Prologue: kc=0 of step 0 in flight before the loop.
    gissue1(b0h, pbh, 0);

#pragma unroll 1
    for (int t = 0; t < S_LEN; ++t) {
        // Defeat LICM of the (t-invariant) streamed loads.
#pragma unroll
        for (int g = 0; g < 3; ++g)
            asm volatile("" : "+v"(pbh[g]));

        const int cur = t & 1, nxt = cur ^ 1;
        const char* Ac = smem + A_OFF + cur * 16384;

        ahread(ahA, Ac, 0, rl);            // A-frags for kc=0
        gissue1(b1h, pbh, 1);              // kc=1 stream in flight

        // x for my 8 rows (LDS broadcast); xidx is wave-uniform per step.
        const int xidx = ((t >> 4) & 1) * 512 + (t & 15);
        float xr[2][4];
#pragma unroll
        for (int mt = 0; mt < 2; ++mt)
#pragma unroll
            for (int r = 0; r < 4; ++r)
                xr[mt][r] = xt[xbase[mt][r] + xidx];

        // C frags [gate][mt]; fold x-side pre-activation + bias into init.
        floatx4 acc[3][2];
#pragma unroll
        for (int mt = 0; mt < 2; ++mt)
#pragma unroll
            for (int r = 0; r < 4; ++r) {
                acc[0][mt][r] = fmaf(xr[mt][r], wih[0], bcc[0]);
                acc[1][mt][r] = fmaf(xr[mt][r], wih[1], bcc[1]);
                acc[2][mt][r] = bhhn;
            }

        // ---- Pipelined kc ladder (single-fp16 stream): consume kc,
        //      stream kc+1, read A(kc+1) ----
        ahread(ahB, Ac, 1, rl);
        kcmfma1(acc, ahA, b0h);                           // kc0
        gissue1(b0h, pbh, 2);
        ahread(ahA, Ac, 2, rl);
        kcmfma1(acc, ahB, b1h);                           // kc1
        gissue1(b1h, pbh, 3);
        ahread(ahB, Ac, 3, rl);
        kcmfma1(acc, ahA, b0h);                           // kc2
        gissue1(b0h, pbh, 4);
        ahread(ahA, Ac, 4, rl);
        kcmfma1(acc, ahB, b1h);                           // kc3
        gissue1(b1h, pbh, 5);
        ahread(ahB, Ac, 5, rl);
        kcmfma1(acc, ahA, b0h);                           // kc4
        ahread(ahA, Ac, 6, rl);
        kcmfma1(acc, ahB, b1h);                           // kc5

        // ---- kc6: hi from the LDS cache (single precision) ----
        {
            half8 w6h[3];
#pragma unroll
            for (int g = 0; g < 3; ++g)
                w6h[g] = *(const half8*)(w6base[g]);
            ahread(ahB, Ac, 7, rl);
            kcmfma1(acc, ahA, w6h);                       // kc6
        }

        // Prefetch next step's kc0 while kc7 + gates + barrier run.
        gissue1(b0h, pbh, 0);
        kcmfma2(acc, ahB, r7h, r7l);                      // kc7 (split)

        // Gates + h update (in-register); scatter next A-frags (rot3-swizzled).
        char* Anx = smem + A_OFF + nxt * 16384;
#pragma unroll
        for (int mt = 0; mt < 2; ++mt) {
            char* ch = Anx + (hchunk + mt) * 1024;        // chunk kc = wv>>1
#pragma unroll
            for (int r = 0; r < 4; ++r) {
                const float rr  = sigmoid_fast(acc[0][mt][r]);
                const float zz  = sigmoid_fast(acc[1][mt][r]);
                const float inn = fmaf(xr[mt][r], wih[2], bihn);
                const float nn  = tanh_fast(fmaf(rr, acc[2][mt][r], inn));
                const float hv  = (1.0f - zz) * nn + zz * h_own[mt][r];
                h_own[mt][r] = hv;
                *(unsigned short*)(ch + soff[r]) = f32_f16(hv);
            }
        }

        // Re-stage x for the next 16 steps (into the idle x buffer).
        const bool tick = ((t & 15) == 15) && (t != S_LEN - 1);
        if (tick && tid < 512) {
            const int r = tid >> 4, t2 = tid & 15;
            xt[((((t + 1) >> 4) & 1) * 32 + r) * 16 + t2] =
                x[(size_t)(row0 + r) * S_LEN + (t + 1) + t2];
        }
        __syncthreads();   // single barrier: next A-frags + x tile visible
    }

    // -------- Epilogue: dump final h (fp32, from registers) and project.
    float* hfin = (float*)(smem);   // reuse A region: [32][256] = 32 KiB
#pragma unroll
    for (int mt = 0; mt < 2; ++mt)
#pragma unroll
        for (int r = 0; r < 4; ++r) {
            const int m = q * 4 + r + 16 * mt;
            const int k = wv * 16 + c;
            hfin[m * H_DIM + k] = h_own[mt][r];
        }
    __syncthreads();

    if (tid < 256) {
        const int cid   = tid & 63;
        const int rid   = tid >> 6;
        const int myrow = rid * 8;
        const int pA    = cid;
        const int pB    = 64 + cid;
        const bool hasB = (cid < 32);
        float accA[8], accB[8];
#pragma unroll
        for (int rr = 0; rr < 8; ++rr) { accA[rr] = 0.0f; accB[rr] = 0.0f; }

        for (int k = 0; k < H_DIM; k += 4) {
            float4 hv[8];
#pragma unroll
            for (int rr = 0; rr < 8; ++rr)
                hv[rr] = *(const float4*)&hfin[(myrow + rr) * H_DIM + k];
            float wA[4], wB[4];
#pragma unroll
            for (int kk = 0; kk < 4; ++kk) {
                wA[kk] = WoT[(size_t)(k + kk) * P_DIM + pA];
                wB[kk] = hasB ? WoT[(size_t)(k + kk) * P_DIM + pB] : 0.0f;
            }
#pragma unroll
            for (int kk = 0; kk < 4; ++kk)
#pragma unroll
                for (int rr = 0; rr < 8; ++rr) {
                    const float hvv = (&hv[rr].x)[kk];
                    accA[rr] = fmaf(hvv, wA[kk], accA[rr]);
                    accB[rr] = fmaf(hvv, wB[kk], accB[rr]);
                }
        }
        const float boA = b_out[pA];
        const float boB = hasB ? b_out[pB] : 0.0f;
#pragma unroll
        for (int rr = 0; rr < 8; ++rr) {
            const size_t orow = (size_t)(row0 + myrow + rr) * P_DIM;
            out[orow + pA] = accA[rr] + boA;
            if (hasB) out[orow + pB] = accB[rr] + boB;
        }
    }
}

// -------- fp32 fallback — used only if ws_size is too small.
__global__ __launch_bounds__(256, 1)
void gru_fallback(const float* __restrict__ x,
                  const float* __restrict__ W_ih,
                  const float* __restrict__ Whh,
                  const float* __restrict__ b_ih,
                  const float* __restrict__ b_hh,
                  const float* __restrict__ Wout,
                  const float* __restrict__ b_out,
                  float* __restrict__ out) {
    __shared__ float hbuf[2][TB][H_DIM];

    const int tid   = threadIdx.x;
    const int cid   = tid & 63;
    const int rid   = tid >> 6;
    const int row0  = blockIdx.x * TB;
    const int myrow = rid * 8;
    const int c0    = cid * 4;

    float wih[3][4], bc[2][4], bihn[4], bhhn[4];
#pragma unroll
    for (int cc = 0; cc < 4; ++cc) {
        const int j = c0 + cc;
        wih[0][cc] = W_ih[j];
        wih[1][cc] = W_ih[H_DIM + j];
        wih[2][cc] = W_ih[2 * H_DIM + j];
        bc[0][cc]  = b_ih[j] + b_hh[j];
        bc[1][cc]  = b_ih[H_DIM + j] + b_hh[H_DIM + j];
        bihn[cc]   = b_ih[2 * H_DIM + j];
        bhhn[cc]   = b_hh[2 * H_DIM + j];
    }
    for (int i = tid; i < TB * H_DIM; i += 256) (&hbuf[0][0][0])[i] = 0.0f;
    float h_own[8][4];
#pragma unroll
    for (int rr = 0; rr < 8; ++rr)
#pragma unroll
        for (int cc = 0; cc < 4; ++cc) h_own[rr][cc] = 0.0f;
    __syncthreads();

    int p = 0;
    for (int t = 0; t < S_LEN; ++t) {
        float xv[8];
#pragma unroll
        for (int rr = 0; rr < 8; ++rr)
            xv[rr] = x[(size_t)(row0 + myrow + rr) * S_LEN + t];

        float acc[3][8][4];
#pragma unroll
        for (int rr = 0; rr < 8; ++rr)
#pragma unroll
            for (int cc = 0; cc < 4; ++cc) {
                acc[0][rr][cc] = fmaf(xv[rr], wih[0][cc], bc[0][cc]);
                acc[1][rr][cc] = fmaf(xv[rr], wih[1][cc], bc[1][cc]);
                acc[2][rr][cc] = bhhn[cc];
            }
        const float* hb = &hbuf[p][0][0];
        for (int k = 0; k < H_DIM; k += 4) {
            float4 hv[8];
#pragma unroll
            for (int rr = 0; rr < 8; ++rr)
                hv[rr] = *(const float4*)(hb + (myrow + rr) * H_DIM + k);
#pragma unroll
            for (int g = 0; g < 3; ++g)
#pragma unroll
                for (int kk = 0; kk < 4; ++kk) {
                    float wrow[4];
#pragma unroll
                    for (int cc = 0; cc < 4; ++cc)
                        wrow[cc] = Whh[(size_t)(g * H_DIM + c0 + cc) * H_DIM + k + kk];
#pragma unroll
                    for (int rr = 0; rr < 8; ++rr) {
                        const float hvv = (&hv[rr].x)[kk];
#pragma unroll
                        for (int cc = 0; cc < 4; ++cc)
                            acc[g][rr][cc] = fmaf(hvv, wrow[cc], acc[g][rr][cc]);
                    }
                }
        }
#pragma unroll
        for (int rr = 0; rr < 8; ++rr) {
            float4 hnew;
#pragma unroll
            for (int cc = 0; cc < 4; ++cc) {
                const float r_  = sigmoid_fast(acc[0][rr][cc]);
                const float z_  = sigmoid_fast(acc[1][rr][cc]);
                const float i_n = fmaf(xv[rr], wih[2][cc], bihn[cc]);
                const float n_  = tanh_fast(fmaf(r_, acc[2][rr][cc], i_n));
                const float hv2 = (1.0f - z_) * n_ + z_ * h_own[rr][cc];
                h_own[rr][cc] = hv2;
                (&hnew.x)[cc] = hv2;
            }
            *(float4*)&hbuf[1 - p][myrow + rr][c0] = hnew;
        }
        __syncthreads();
        p ^= 1;
    }

    const int  pA   = cid;
    const int  pB   = 64 + cid;
    const bool hasB = (cid < 32);
    float accA[8], accB[8];
#pragma unroll
    for (int rr = 0; rr < 8; ++rr) { accA[rr] = 0.0f; accB[rr] = 0.0f; }
    for (int k = 0; k < H_DIM; k += 4) {
        float4 hv[8];
#pragma unroll
        for (int rr = 0; rr < 8; ++rr)
            hv[rr] = *(const float4*)&hbuf[p][myrow + rr][k];
        float wA[4], wB[4];
#pragma unroll
        for (int kk = 0; kk < 4; ++kk) {
            wA[kk] = Wout[(size_t)pA * H_DIM + k + kk];
            wB[kk] = hasB ? Wout[(size_t)pB * H_DIM + k + kk] : 0.0f;
        }
#pragma unroll
        for (int kk = 0; kk < 4; ++kk)
#pragma unroll
            for (int rr = 0; rr < 8; ++rr) {
                const float hvv = (&hv[rr].x)[kk];
                accA[rr] = fmaf(hvv, wA[kk], accA[rr]);
                accB[rr] = fmaf(hvv, wB[kk], accB[rr]);
            }
    }
    const float boA = b_out[pA];
    const float boB = hasB ? b_out[pB] : 0.0f;
#pragma unroll
    for (int rr = 0; rr < 8; ++rr) {
        const size_t orow = (size_t)(row0 + myrow + rr) * P_DIM;
        out[orow + pA] = accA[rr] + boA;
        if (hasB) out[orow + pB] = accB[rr] + boB;
    }
}

extern "C" void kernel_launch(void* const* d_in, const int* in_sizes, int n_in,
                              void* d_out, int out_size, void* d_ws, size_t ws_size,
                              hipStream_t stream) {
    const float* x     = (const float*)d_in[0];
    const float* W_ih  = (const float*)d_in[1];
    const float* W_hh  = (const float*)d_in[2];
    const float* b_ih  = (const float*)d_in[3];
    const float* b_hh  = (const float*)d_in[4];
    const float* W_out = (const float*)d_in[5];
    const float* b_out = (const float*)d_in[6];
    float* out = (float*)d_out;

    const size_t bpack_elems = 8 * 48 * 64 * 8;          // 196608 f16 per matrix
    const size_t wot_elems   = (size_t)H_DIM * P_DIM;    // 24576 fp32
    const size_t ctr_off = bpack_elems * 2 * sizeof(unsigned short) * 2 +
                           wot_elems * sizeof(float);    // 1671168 B (16-aligned)
    const size_t need = ctr_off + sizeof(unsigned int);

    if (ws_size >= need) {
        unsigned short* Bh = (unsigned short*)d_ws;
        unsigned short* Bl = Bh + bpack_elems * 2;
        float* WoT = (float*)(Bl + bpack_elems * 2);
        unsigned int* ctr = (unsigned int*)((char*)d_ws + ctr_off);
        pack_weights<<<G3, H_DIM, 0, stream>>>(W_hh, W_out, Bh, Bl, WoT, ctr);
        gru_mfma<<<B_ROWS / TB, 1024, 0, stream>>>(x, W_ih, b_ih, b_hh,
                                                   Bh, Bl, WoT, b_out, out, ctr);
    } else {
        gru_fallback<<<B_ROWS / TB, 256, 0, stream>>>(x, W_ih, W_hh, b_ih, b_hh,
                                                      W_out, b_out, out);
    }
}